// Round 9
// baseline (506.875 us; speedup 1.0000x reference)
//
#include <hip/hip_runtime.h>
#include <math.h>

#define B_ 64
#define N_ 4096
#define D_ 128
#define S_ 7
#define H_ 256
#define ITERS_ 3
#define AP 132      // padded fp32 LDS row stride
#define NCHUNK 8    // j-chunks per batch (512 rows each) -> grid 512 = exactly 2 blocks/CU

__device__ __forceinline__ float dot4(float4 a, float4 b) {
  return a.x * b.x + a.y * b.y + a.z * b.z + a.w * b.w;
}
__device__ __forceinline__ float4 ld4(const float* p) {
  return *reinterpret_cast<const float4*>(p);
}

// ---------------- K0: slots = mu + sigma * noise ----------------
__global__ void k_init(const float* __restrict__ noise, const float* __restrict__ mu,
                       const float* __restrict__ sigma, float* __restrict__ slots) {
  int idx = blockIdx.x * 256 + threadIdx.x;  // 57344 total
  int d = idx & 127;
  slots[idx] = mu[d] + sigma[d] * noise[idx];
}

// ---------------- K0b: transpose a weight matrix W[R][C] into T4 fragment order --------
__global__ void k_wt(const float* __restrict__ W, float* __restrict__ out, int R, int C) {
  int idx = blockIdx.x * 256 + threadIdx.x;
  if (idx >= R * C) return;
  int d = idx / C, i = idx - d * C;
  out[(((i >> 2) * R + d) << 2) + (i & 3)] = W[idx];
}

// ---------------- K2 (prologue only, it=0): q = LN(slots)@Wq^T + bq;  q' = q@Wk ----------------
__global__ __launch_bounds__(128) void k_q(
    const float* __restrict__ slots, const float* __restrict__ Wq, const float* __restrict__ bq,
    const float* __restrict__ g, const float* __restrict__ b,
    const float* __restrict__ Wk, float* __restrict__ qp) {
  __shared__ __align__(16) float lns[AP];
  __shared__ __align__(16) float qs2[AP];
  __shared__ float red[4];
  int row = blockIdx.x;  // b*7+s
  int d = threadIdx.x;
  float x = slots[row * D_ + d];
  float s1 = x, s2 = x * x;
#pragma unroll
  for (int off = 32; off >= 1; off >>= 1) { s1 += __shfl_down(s1, off); s2 += __shfl_down(s2, off); }
  if ((d & 63) == 0) { red[(d >> 6) * 2] = s1; red[(d >> 6) * 2 + 1] = s2; }
  __syncthreads();
  float sum = red[0] + red[2], sumsq = red[1] + red[3];
  float mean = sum * (1.f / 128.f);
  float var = sumsq * (1.f / 128.f) - mean * mean;
  float rs = rsqrtf(var + 1e-5f);
  lns[d] = (x - mean) * rs * g[d] + b[d];
  __syncthreads();
  const float* w = Wq + d * D_;
  float acc = bq[d];
  for (int i4 = 0; i4 < D_; i4 += 4) acc += dot4(*reinterpret_cast<const float4*>(&lns[i4]), ld4(w + i4));
  qs2[d] = acc;
  __syncthreads();
  float qpa = 0.f;
#pragma unroll 4
  for (int dd = 0; dd < D_; dd++) qpa += qs2[dd] * Wk[dd * D_ + d];
  qp[row * D_ + d] = qpa;
}

// ---------------- K3: fused LN + flash attention over one j-chunk of 512 ----------------
// q' slices are read via wave-uniform global loads (readfirstlane -> s_load path,
// scalar cache) instead of LDS: removes ~56 ds_read_b128 per wave per sub from
// the saturated LDS pipe. Values + sum tree bit-identical to the LDS version.
__global__ __launch_bounds__(256) void k_attn(
    const float* __restrict__ qpbuf, const float* __restrict__ emb,
    const float* __restrict__ lng, const float* __restrict__ lnb,
    float* __restrict__ partialA, float* __restrict__ partialM, float* __restrict__ partialS) {
  __shared__ __align__(16) float vt[64 * AP];   // LN tile (K and V); reused as redf at end
  __shared__ float red[28 * 64];                // logit partials [g*7+s][j]
  __shared__ float pt[7 * 64];                  // combined logits -> exp weights
  __shared__ float sm[7], ssum[7], tmax[7];
  int t = threadIdx.x;
  int b = blockIdx.x >> 3, jc = blockIdx.x & (NCHUNK - 1);

  if (t < 7) { sm[t] = -1e30f; ssum[t] = 0.f; }

  int j = t & 63, g = t >> 6;                   // logits roles
  int gu = __builtin_amdgcn_readfirstlane(g);   // wave-uniform col-group -> SGPR q reads
  const float* qb = qpbuf + (long)(b * 7) * D_ + gu * 32;
  int d4 = (t & 31) * 4, jg = t >> 5;           // update roles
  int ln_i4 = (t & 31) * 4;
  int ln_r8 = t >> 5;
  float4 gv = ld4(&lng[ln_i4]);
  float4 bv4 = ld4(&lnb[ln_i4]);

  float acc[7][4];
#pragma unroll
  for (int s = 0; s < 7; s++)
#pragma unroll
    for (int c = 0; c < 4; c++) acc[s][c] = 0.f;
  __syncthreads();

  for (int sub = 0; sub < 8; sub++) {
    int j0 = jc * 512 + sub * 64;
    // stage + LN: 32 contiguous half-wave threads own one row
#pragma unroll
    for (int u = 0; u < 8; u++) {
      int row = u * 8 + ln_r8;
      float4 x = ld4(&emb[((long)b * N_ + j0 + row) * D_ + ln_i4]);
      float s1 = x.x + x.y + x.z + x.w;
      float s2 = dot4(x, x);
#pragma unroll
      for (int off = 16; off >= 1; off >>= 1) {
        s1 += __shfl_xor(s1, off, 32);
        s2 += __shfl_xor(s2, off, 32);
      }
      float mean = s1 * (1.f / 128.f);
      float var = s2 * (1.f / 128.f) - mean * mean;
      float rs = rsqrtf(var + 1e-5f);
      float4 o;
      o.x = (x.x - mean) * rs * gv.x + bv4.x;
      o.y = (x.y - mean) * rs * gv.y + bv4.y;
      o.z = (x.z - mean) * rs * gv.z + bv4.z;
      o.w = (x.w - mean) * rs * gv.w + bv4.w;
      *reinterpret_cast<float4*>(&vt[row * AP + ln_i4]) = o;
    }
    __syncthreads();

    // logits partial dots; q slices via uniform (scalar-path) global loads
    float acc7[7];
#pragma unroll
    for (int s = 0; s < 7; s++) acc7[s] = 0.f;
#pragma unroll
    for (int st = 0; st < 8; st++) {
      float4 kv = *reinterpret_cast<const float4*>(&vt[j * AP + gu * 32 + st * 4]);
#pragma unroll
      for (int s = 0; s < 7; s++) {
        float4 qv = ld4(qb + s * D_ + st * 4);
        acc7[s] += dot4(kv, qv);
      }
    }
#pragma unroll
    for (int s = 0; s < 7; s++) red[(g * 7 + s) * 64 + j] = acc7[s];
    __syncthreads();

    // combine 4 partials -> raw logits (identical sum order)
    for (int pp = t; pp < 448; pp += 256) {
      int s = pp >> 6, jj = pp & 63;
      pt[pp] = red[s * 64 + jj] + red[(7 + s) * 64 + jj] +
               red[(14 + s) * 64 + jj] + red[(21 + s) * 64 + jj];
    }
    __syncthreads();

    // tile max per s
    if (t < 224) {
      int s = t >> 5, i = t & 31;
      float m = fmaxf(pt[s * 64 + i], pt[s * 64 + 32 + i]);
#pragma unroll
      for (int off = 16; off >= 1; off >>= 1) m = fmaxf(m, __shfl_down(m, off, 32));
      if ((t & 31) == 0) tmax[s] = m;
    }
    __syncthreads();

    // rescale acc; exponentiate logits
#pragma unroll
    for (int s = 0; s < 7; s++) {
      float mnew = fmaxf(sm[s], tmax[s]);
      float scl = __expf(sm[s] - mnew);
#pragma unroll
      for (int c = 0; c < 4; c++) acc[s][c] *= scl;
    }
    for (int pp = t; pp < 448; pp += 256) {
      int s = pp >> 6;
      float mnew = fmaxf(sm[s], tmax[s]);
      pt[pp] = __expf(pt[pp] - mnew);
    }
    __syncthreads();

    // chunk sum + state update
    if (t < 224) {
      int s = t >> 5, i = t & 31;
      float ssub = pt[s * 64 + i] + pt[s * 64 + 32 + i];
#pragma unroll
      for (int off = 16; off >= 1; off >>= 1) ssub += __shfl_down(ssub, off, 32);
      if ((t & 31) == 0) {
        float mnew = fmaxf(sm[s], tmax[s]);
        float scl = __expf(sm[s] - mnew);
        ssum[s] = ssum[s] * scl + ssub;
        sm[s] = mnew;
      }
    }

    // V-accumulate
#pragma unroll
    for (int jl = 0; jl < 8; jl++) {
      int jj = jg * 8 + jl;
      float4 vv = *reinterpret_cast<const float4*>(&vt[jj * AP + d4]);
#pragma unroll
      for (int s = 0; s < 7; s++) {
        float e = pt[s * 64 + jj];
        acc[s][0] += e * vv.x; acc[s][1] += e * vv.y;
        acc[s][2] += e * vv.z; acc[s][3] += e * vv.w;
      }
    }
    __syncthreads();
  }

  // cross-jg reduction (reuse vt)
  float* redf = vt;
#pragma unroll
  for (int s = 0; s < 7; s++)
    *reinterpret_cast<float4*>(&redf[(jg * 7 + s) * 128 + d4]) =
        make_float4(acc[s][0], acc[s][1], acc[s][2], acc[s][3]);
  __syncthreads();
  for (int pp = t; pp < 896; pp += 256) {
    int s = pp >> 7, d = pp & 127;
    float x = 0.f;
#pragma unroll
    for (int g2 = 0; g2 < 8; g2++) x += redf[(g2 * 7 + s) * 128 + d];
    partialA[((long)(b * NCHUNK + jc) * 7 + s) * 128 + d] = x;
  }
  if (t < 7) {
    partialM[(b * NCHUNK + jc) * 7 + t] = sm[t];
    partialS[(b * NCHUNK + jc) * 7 + t] = ssum[t];
  }
}

// ---------------- K4: flash combine + Wv + GRU + LN + FFN + fused next-q ----------------
__global__ __launch_bounds__(256) void k_gruffq(
    const float* __restrict__ partialA, const float* __restrict__ partialM,
    const float* __restrict__ partialS, float* __restrict__ slots,
    const float* __restrict__ wtV, const float* __restrict__ bv,
    const float* __restrict__ wtIH, const float* __restrict__ wtHH,
    const float* __restrict__ bih, const float* __restrict__ bhh,
    const float* __restrict__ wt1, const float* __restrict__ b1,
    const float* __restrict__ wt2, const float* __restrict__ b2,
    const float* __restrict__ gff, const float* __restrict__ bff,
    const float* __restrict__ lsg, const float* __restrict__ lsb,
    const float* __restrict__ wtQ, const float* __restrict__ bq,
    const float* __restrict__ Wk, float* __restrict__ qp, int compute_q) {
  __shared__ __align__(16) float us[AP];
  __shared__ __align__(16) float xs[AP];
  __shared__ __align__(16) float hs[AP];
  __shared__ __align__(16) float nss[AP];
  __shared__ __align__(16) float lns[AP];
  __shared__ __align__(16) float sn[AP];
  __shared__ __align__(16) float qv[AP];
  __shared__ __align__(16) float h1s[H_];
  __shared__ __align__(16) float g6[6 * 128];
  __shared__ __align__(16) float pp[2 * 128];
  __shared__ float den2[2];
  __shared__ float red2[2];
  int t = threadIdx.x;
  int d = t & 127, h = t >> 7;
  int blk = blockIdx.x;
  int b = blk / 7, s = blk % 7;

  // ---- flash combine over NCHUNK chunks (split across h) ----
  float mg = -1e30f;
#pragma unroll
  for (int c = 0; c < NCHUNK; c++) mg = fmaxf(mg, partialM[(b * NCHUNK + c) * 7 + s]);
  float up = 0.f, den = 0.f;
#pragma unroll
  for (int cc = 0; cc < NCHUNK / 2; cc++) {
    int c = h * (NCHUNK / 2) + cc;
    float w = __expf(partialM[(b * NCHUNK + c) * 7 + s] - mg);
    den += w * partialS[(b * NCHUNK + c) * 7 + s];
    up += w * partialA[((long)(b * NCHUNK + c) * 7 + s) * 128 + d];
  }
  pp[h * 128 + d] = up;
  if (d == 0) den2[h] = den;
  if (h == 1) hs[d] = slots[blk * D_ + d];
  __syncthreads();
  if (h == 0) us[d] = (pp[d] + pp[128 + d]) / (den2[0] + den2[1]);
  __syncthreads();

  // ---- updates x = bv + us . Wv[d,:]  (split-K over h; coalesced T4 loads) ----
  {
    float acc = 0.f;
#pragma unroll
    for (int k = 0; k < 16; k++) {
      int i4 = h * 16 + k;
      acc += dot4(*reinterpret_cast<const float4*>(&us[i4 * 4]),
                  ld4(wtV + (i4 * 128 + d) * 4));
    }
    pp[h * 128 + d] = acc;
  }
  __syncthreads();
  if (h == 0) xs[d] = bv[d] + pp[d] + pp[128 + d];
  __syncthreads();

  // ---- GRU: h==0 -> gi over xs (wtIH), h==1 -> gh over hs (wtHH); R=384 ----
  {
    const float* wt = (h == 0) ? wtIH : wtHH;
    const float* bias = (h == 0) ? bih : bhh;
    const float* vec = (h == 0) ? xs : hs;
    float a0 = bias[d], a1 = bias[128 + d], a2 = bias[256 + d];
#pragma unroll
    for (int i4 = 0; i4 < 32; i4++) {
      float4 v = *reinterpret_cast<const float4*>(&vec[i4 * 4]);
      a0 += dot4(v, ld4(wt + (i4 * 384 + d) * 4));
      a1 += dot4(v, ld4(wt + (i4 * 384 + 128 + d) * 4));
      a2 += dot4(v, ld4(wt + (i4 * 384 + 256 + d) * 4));
    }
    g6[(h * 3 + 0) * 128 + d] = a0;
    g6[(h * 3 + 1) * 128 + d] = a1;
    g6[(h * 3 + 2) * 128 + d] = a2;
  }
  __syncthreads();
  if (h == 0) {
    float gir = g6[d], giz = g6[128 + d], gin = g6[256 + d];
    float ghr = g6[384 + d], ghz = g6[512 + d], ghn = g6[640 + d];
    float r = 1.f / (1.f + __expf(-(gir + ghr)));
    float z = 1.f / (1.f + __expf(-(giz + ghz)));
    float n = tanhf(gin + r * ghn);
    nss[d] = (1.f - z) * n + z * hs[d];
  }
  __syncthreads();

  // ---- LN_ff over nss ----
  if (t < 64) {
    float v0 = nss[t], v1 = nss[t + 64];
    float s1 = v0 + v1, s2 = v0 * v0 + v1 * v1;
#pragma unroll
    for (int off = 32; off >= 1; off >>= 1) { s1 += __shfl_down(s1, off); s2 += __shfl_down(s2, off); }
    if (t == 0) { red2[0] = s1; red2[1] = s2; }
  }
  __syncthreads();
  {
    float mean = red2[0] * (1.f / 128.f);
    float var = red2[1] * (1.f / 128.f) - mean * mean;
    float rs = rsqrtf(var + 1e-5f);
    if (h == 0) lns[d] = (nss[d] - mean) * rs * gff[d] + bff[d];
  }
  __syncthreads();

  // ---- FFN1: 256 outputs, one per thread (wt1, R=256) ----
  {
    float a = b1[t];
#pragma unroll
    for (int i4 = 0; i4 < 32; i4++)
      a += dot4(*reinterpret_cast<const float4*>(&lns[i4 * 4]),
                ld4(wt1 + (i4 * 256 + t) * 4));
    h1s[t] = fmaxf(a, 0.f);
  }
  __syncthreads();

  // ---- FFN2 + residual (split-K over h; wt2, R=128) ----
  {
    float acc = 0.f;
#pragma unroll
    for (int k = 0; k < 32; k++) {
      int h4 = h * 32 + k;
      acc += dot4(*reinterpret_cast<const float4*>(&h1s[h4 * 4]),
                  ld4(wt2 + (h4 * 128 + d) * 4));
    }
    pp[h * 128 + d] = acc;
  }
  __syncthreads();
  if (h == 0) {
    float out = nss[d] + b2[d] + pp[d] + pp[128 + d];
    sn[d] = out;
    slots[blk * D_ + d] = out;
  }
  __syncthreads();

  if (!compute_q) return;

  // ---- fused next-iteration q: LN_s(sn) -> q -> q' = q@Wk ----
  if (t < 64) {
    float v0 = sn[t], v1 = sn[t + 64];
    float s1 = v0 + v1, s2 = v0 * v0 + v1 * v1;
#pragma unroll
    for (int off = 32; off >= 1; off >>= 1) { s1 += __shfl_down(s1, off); s2 += __shfl_down(s2, off); }
    if (t == 0) { red2[0] = s1; red2[1] = s2; }
  }
  __syncthreads();
  {
    float mean = red2[0] * (1.f / 128.f);
    float var = red2[1] * (1.f / 128.f) - mean * mean;
    float rs = rsqrtf(var + 1e-5f);
    if (h == 0) lns[d] = (sn[d] - mean) * rs * lsg[d] + lsb[d];
  }
  __syncthreads();
  {
    float acc = 0.f;
#pragma unroll
    for (int k = 0; k < 16; k++) {
      int i4 = h * 16 + k;
      acc += dot4(*reinterpret_cast<const float4*>(&lns[i4 * 4]),
                  ld4(wtQ + (i4 * 128 + d) * 4));
    }
    pp[h * 128 + d] = acc;
  }
  __syncthreads();
  if (h == 0) qv[d] = bq[d] + pp[d] + pp[128 + d];
  __syncthreads();
  {
    float acc = 0.f;
    const float* wc = Wk + h * 64 * D_ + d;
#pragma unroll 4
    for (int dd = 0; dd < 64; dd++) acc += qv[h * 64 + dd] * wc[dd * D_];
    pp[h * 128 + d] = acc;
  }
  __syncthreads();
  if (h == 0) qp[blk * D_ + d] = pp[d] + pp[128 + d];
}

extern "C" void kernel_launch(void* const* d_in, const int* in_sizes, int n_in,
                              void* d_out, int out_size, void* d_ws, size_t ws_size,
                              hipStream_t stream) {
  const float* emb   = (const float*)d_in[0];
  const float* noise = (const float*)d_in[1];
  const float* mu    = (const float*)d_in[2];
  const float* sigma = (const float*)d_in[3];
  const float* Wk = (const float*)d_in[4];  const float* bk = (const float*)d_in[5];
  const float* Wq = (const float*)d_in[6];  const float* bq = (const float*)d_in[7];
  const float* Wv = (const float*)d_in[8];  const float* bv = (const float*)d_in[9];
  const float* Wih = (const float*)d_in[10]; const float* Whh = (const float*)d_in[11];
  const float* bih = (const float*)d_in[12]; const float* bhh = (const float*)d_in[13];
  const float* W1 = (const float*)d_in[14];  const float* b1 = (const float*)d_in[15];
  const float* W2 = (const float*)d_in[16];  const float* b2 = (const float*)d_in[17];
  const float* lin_g = (const float*)d_in[18]; const float* lin_b = (const float*)d_in[19];
  const float* ls_g  = (const float*)d_in[20]; const float* ls_b  = (const float*)d_in[21];
  const float* lff_g = (const float*)d_in[22]; const float* lff_b = (const float*)d_in[23];
  (void)bk;  // q.bk is softmax-invariant (cancels exactly)

  float* slots = (float*)d_out;  // [B,S,D] in d_out, updated in place
  float* qp       = (float*)d_ws;                              // 57,344 f
  float* partialA = qp + (size_t)B_ * S_ * D_;                 // 458,752 f
  float* partialM = partialA + (size_t)B_ * NCHUNK * S_ * D_;  // 3,584 f
  float* partialS = partialM + (size_t)B_ * NCHUNK * S_;       // 3,584 f
  // transposed weights (786 KB total), written once in the prologue
  float* wtV  = partialS + (size_t)B_ * NCHUNK * S_;           // 16,384 f
  float* wtIH = wtV + 16384;                                   // 49,152 f
  float* wtHH = wtIH + 49152;                                  // 49,152 f
  float* wtQ  = wtHH + 49152;                                  // 16,384 f
  float* wt1  = wtQ + 16384;                                   // 32,768 f
  float* wt2  = wt1 + 32768;                                   // 32,768 f

  k_init<<<224, 256, 0, stream>>>(noise, mu, sigma, slots);
  k_wt<<<64, 256, 0, stream>>>(Wv, wtV, 128, 128);
  k_wt<<<192, 256, 0, stream>>>(Wih, wtIH, 384, 128);
  k_wt<<<192, 256, 0, stream>>>(Whh, wtHH, 384, 128);
  k_wt<<<64, 256, 0, stream>>>(Wq, wtQ, 128, 128);
  k_wt<<<128, 256, 0, stream>>>(W1, wt1, 256, 128);
  k_wt<<<128, 256, 0, stream>>>(W2, wt2, 128, 256);
  k_q<<<448, 128, 0, stream>>>(slots, Wq, bq, ls_g, ls_b, Wk, qp);
  for (int it = 0; it < ITERS_; it++) {
    k_attn<<<B_ * NCHUNK, 256, 0, stream>>>(qp, emb, lin_g, lin_b, partialA, partialM, partialS);
    k_gruffq<<<448, 256, 0, stream>>>(partialA, partialM, partialS, slots, wtV, bv,
                                      wtIH, wtHH, bih, bhh, wt1, b1, wt2, b2, lff_g, lff_b,
                                      ls_g, ls_b, wtQ, bq, Wk, qp, it < ITERS_ - 1 ? 1 : 0);
  }
}

// Round 10
// 444.467 us; speedup vs baseline: 1.1404x; 1.1404x over previous
//
#include <hip/hip_runtime.h>
#include <math.h>

#define B_ 64
#define N_ 4096
#define D_ 128
#define S_ 7
#define H_ 256
#define ITERS_ 3
#define AP 132      // padded fp32 LDS row stride
#define NCHUNK 8    // j-chunks per batch (512 rows each) -> grid 512 = exactly 2 blocks/CU

__device__ __forceinline__ float dot4(float4 a, float4 b) {
  return a.x * b.x + a.y * b.y + a.z * b.z + a.w * b.w;
}
__device__ __forceinline__ float4 ld4(const float* p) {
  return *reinterpret_cast<const float4*>(p);
}

// ---------------- K0: slots = mu + sigma * noise ----------------
__global__ void k_init(const float* __restrict__ noise, const float* __restrict__ mu,
                       const float* __restrict__ sigma, float* __restrict__ slots) {
  int idx = blockIdx.x * 256 + threadIdx.x;  // 57344 total
  int d = idx & 127;
  slots[idx] = mu[d] + sigma[d] * noise[idx];
}

// ---------------- K0b: transpose a weight matrix W[R][C] into T4 fragment order --------
__global__ void k_wt(const float* __restrict__ W, float* __restrict__ out, int R, int C) {
  int idx = blockIdx.x * 256 + threadIdx.x;
  if (idx >= R * C) return;
  int d = idx / C, i = idx - d * C;
  out[(((i >> 2) * R + d) << 2) + (i & 3)] = W[idx];
}

// ---------------- K2 (prologue only, it=0): q = LN(slots)@Wq^T + bq;  q' = q@Wk ----------------
__global__ __launch_bounds__(128) void k_q(
    const float* __restrict__ slots, const float* __restrict__ Wq, const float* __restrict__ bq,
    const float* __restrict__ g, const float* __restrict__ b,
    const float* __restrict__ Wk, float* __restrict__ qp) {
  __shared__ __align__(16) float lns[AP];
  __shared__ __align__(16) float qs2[AP];
  __shared__ float red[4];
  int row = blockIdx.x;  // b*7+s
  int d = threadIdx.x;
  float x = slots[row * D_ + d];
  float s1 = x, s2 = x * x;
#pragma unroll
  for (int off = 32; off >= 1; off >>= 1) { s1 += __shfl_down(s1, off); s2 += __shfl_down(s2, off); }
  if ((d & 63) == 0) { red[(d >> 6) * 2] = s1; red[(d >> 6) * 2 + 1] = s2; }
  __syncthreads();
  float sum = red[0] + red[2], sumsq = red[1] + red[3];
  float mean = sum * (1.f / 128.f);
  float var = sumsq * (1.f / 128.f) - mean * mean;
  float rs = rsqrtf(var + 1e-5f);
  lns[d] = (x - mean) * rs * g[d] + b[d];
  __syncthreads();
  const float* w = Wq + d * D_;
  float acc = bq[d];
  for (int i4 = 0; i4 < D_; i4 += 4) acc += dot4(*reinterpret_cast<const float4*>(&lns[i4]), ld4(w + i4));
  qs2[d] = acc;
  __syncthreads();
  float qpa = 0.f;
#pragma unroll 4
  for (int dd = 0; dd < D_; dd++) qpa += qs2[dd] * Wk[dd * D_ + d];
  qp[row * D_ + d] = qpa;
}

// ---------------- K3: barrier-free fused LN + flash attention ----------------
// 16-lane group owns 32 rows fully in registers: load (512B coalesced per group),
// LN + logits via width-16 shfl reduces, online softmax state + V-accumulator in
// VGPRs. No LDS / no __syncthreads in the hot loop (the old version had 48
// block-wide rendezvous). Epilogue: flash-merge the 16 group-states (3 barriers).
__global__ __launch_bounds__(256) void k_attn(
    const float* __restrict__ qpbuf, const float* __restrict__ emb,
    const float* __restrict__ lng, const float* __restrict__ lnb,
    float* __restrict__ partialA, float* __restrict__ partialM, float* __restrict__ partialS) {
  __shared__ __align__(16) float lacc[16 * 7 * 128];  // 57,344 B
  __shared__ float lm[16 * 7], lsm[16 * 7];
  __shared__ float wgt[7 * 16];
  __shared__ float mstar[7];
  int t = threadIdx.x;
  int b = blockIdx.x >> 3, jc = blockIdx.x & (NCHUNK - 1);
  int lane = t & 63;
  int gid = (t >> 6) * 4 + (lane >> 4);  // 16 groups of 16 lanes
  int li = lane & 15;
  int i8 = li * 8;                       // this lane's 8-col slice

  // per-lane constants: q' slices, LN gamma/beta
  float4 q0[7], q1[7];
#pragma unroll
  for (int s = 0; s < 7; s++) {
    q0[s] = ld4(&qpbuf[(b * 7 + s) * D_ + i8]);
    q1[s] = ld4(&qpbuf[(b * 7 + s) * D_ + i8 + 4]);
  }
  float4 gv0 = ld4(&lng[i8]), gv1 = ld4(&lng[i8 + 4]);
  float4 bv0 = ld4(&lnb[i8]), bv1 = ld4(&lnb[i8 + 4]);

  float acc[7][8];
#pragma unroll
  for (int s = 0; s < 7; s++)
#pragma unroll
    for (int c = 0; c < 8; c++) acc[s][c] = 0.f;
  float m[7], ssum[7];
#pragma unroll
  for (int s = 0; s < 7; s++) { m[s] = -1e30f; ssum[s] = 0.f; }

  // this group's 32 rows
  const float* src = emb + ((long)b * N_ + jc * 512 + gid * 32) * D_ + i8;
  float4 x0 = ld4(src), x1 = ld4(src + 4);
  for (int i = 0; i < 32; i++) {
    float4 c0 = x0, c1 = x1;
    if (i < 31) {  // 1-deep prefetch: next row's load hides under this row's math
      x0 = ld4(src + (i + 1) * D_);
      x1 = ld4(src + (i + 1) * D_ + 4);
    }
    // LN across the 16-lane group
    float s1 = c0.x + c0.y + c0.z + c0.w + c1.x + c1.y + c1.z + c1.w;
    float s2 = dot4(c0, c0) + dot4(c1, c1);
#pragma unroll
    for (int off = 8; off >= 1; off >>= 1) {
      s1 += __shfl_xor(s1, off, 16);
      s2 += __shfl_xor(s2, off, 16);
    }
    float mean = s1 * (1.f / 128.f);
    float var = s2 * (1.f / 128.f) - mean * mean;
    float rs = rsqrtf(var + 1e-5f);
    float4 o0, o1;
    o0.x = (c0.x - mean) * rs * gv0.x + bv0.x;
    o0.y = (c0.y - mean) * rs * gv0.y + bv0.y;
    o0.z = (c0.z - mean) * rs * gv0.z + bv0.z;
    o0.w = (c0.w - mean) * rs * gv0.w + bv0.w;
    o1.x = (c1.x - mean) * rs * gv1.x + bv1.x;
    o1.y = (c1.y - mean) * rs * gv1.y + bv1.y;
    o1.z = (c1.z - mean) * rs * gv1.z + bv1.z;
    o1.w = (c1.w - mean) * rs * gv1.w + bv1.w;
    // 7 logits + online softmax + V-accumulate, all in registers
#pragma unroll
    for (int s = 0; s < 7; s++) {
      float p = dot4(o0, q0[s]) + dot4(o1, q1[s]);
#pragma unroll
      for (int off = 8; off >= 1; off >>= 1) p += __shfl_xor(p, off, 16);
      float mnew = fmaxf(m[s], p);
      float scl = __expf(m[s] - mnew);
      float e = __expf(p - mnew);
      m[s] = mnew;
      ssum[s] = ssum[s] * scl + e;
      acc[s][0] = acc[s][0] * scl + e * o0.x;
      acc[s][1] = acc[s][1] * scl + e * o0.y;
      acc[s][2] = acc[s][2] * scl + e * o0.z;
      acc[s][3] = acc[s][3] * scl + e * o0.w;
      acc[s][4] = acc[s][4] * scl + e * o1.x;
      acc[s][5] = acc[s][5] * scl + e * o1.y;
      acc[s][6] = acc[s][6] * scl + e * o1.z;
      acc[s][7] = acc[s][7] * scl + e * o1.w;
    }
  }

  // ---- epilogue: flash-merge the 16 group-states ----
#pragma unroll
  for (int s = 0; s < 7; s++) {
    *reinterpret_cast<float4*>(&lacc[(gid * 7 + s) * 128 + i8]) =
        make_float4(acc[s][0], acc[s][1], acc[s][2], acc[s][3]);
    *reinterpret_cast<float4*>(&lacc[(gid * 7 + s) * 128 + i8 + 4]) =
        make_float4(acc[s][4], acc[s][5], acc[s][6], acc[s][7]);
  }
  if (li == 0) {
#pragma unroll
    for (int s = 0; s < 7; s++) { lm[gid * 7 + s] = m[s]; lsm[gid * 7 + s] = ssum[s]; }
  }
  __syncthreads();
  if (t < 7) {
    float mx = -1e30f;
#pragma unroll
    for (int g2 = 0; g2 < 16; g2++) mx = fmaxf(mx, lm[g2 * 7 + t]);
    mstar[t] = mx;
  }
  __syncthreads();
  if (t < 112) {
    int s = t >> 4, g2 = t & 15;
    wgt[s * 16 + g2] = __expf(lm[g2 * 7 + s] - mstar[s]);
  }
  __syncthreads();
  if (t < 7) {
    float dsum = 0.f;
#pragma unroll
    for (int g2 = 0; g2 < 16; g2++) dsum += wgt[t * 16 + g2] * lsm[g2 * 7 + t];
    partialM[(b * NCHUNK + jc) * 7 + t] = mstar[t];
    partialS[(b * NCHUNK + jc) * 7 + t] = dsum;
  }
  for (int pp = t; pp < 896; pp += 256) {
    int s = pp >> 7, d = pp & 127;
    float x = 0.f;
#pragma unroll
    for (int g2 = 0; g2 < 16; g2++) x += wgt[s * 16 + g2] * lacc[(g2 * 7 + s) * 128 + d];
    partialA[((long)(b * NCHUNK + jc) * 7 + s) * 128 + d] = x;
  }
}

// ---------------- K4: flash combine + Wv + GRU + LN + FFN + fused next-q ----------------
__global__ __launch_bounds__(256) void k_gruffq(
    const float* __restrict__ partialA, const float* __restrict__ partialM,
    const float* __restrict__ partialS, float* __restrict__ slots,
    const float* __restrict__ wtV, const float* __restrict__ bv,
    const float* __restrict__ wtIH, const float* __restrict__ wtHH,
    const float* __restrict__ bih, const float* __restrict__ bhh,
    const float* __restrict__ wt1, const float* __restrict__ b1,
    const float* __restrict__ wt2, const float* __restrict__ b2,
    const float* __restrict__ gff, const float* __restrict__ bff,
    const float* __restrict__ lsg, const float* __restrict__ lsb,
    const float* __restrict__ wtQ, const float* __restrict__ bq,
    const float* __restrict__ Wk, float* __restrict__ qp, int compute_q) {
  __shared__ __align__(16) float us[AP];
  __shared__ __align__(16) float xs[AP];
  __shared__ __align__(16) float hs[AP];
  __shared__ __align__(16) float nss[AP];
  __shared__ __align__(16) float lns[AP];
  __shared__ __align__(16) float sn[AP];
  __shared__ __align__(16) float qv[AP];
  __shared__ __align__(16) float h1s[H_];
  __shared__ __align__(16) float g6[6 * 128];
  __shared__ __align__(16) float pp[2 * 128];
  __shared__ float den2[2];
  __shared__ float red2[2];
  int t = threadIdx.x;
  int d = t & 127, h = t >> 7;
  int blk = blockIdx.x;
  int b = blk / 7, s = blk % 7;

  // ---- flash combine over NCHUNK chunks (split across h) ----
  float mg = -1e30f;
#pragma unroll
  for (int c = 0; c < NCHUNK; c++) mg = fmaxf(mg, partialM[(b * NCHUNK + c) * 7 + s]);
  float up = 0.f, den = 0.f;
#pragma unroll
  for (int cc = 0; cc < NCHUNK / 2; cc++) {
    int c = h * (NCHUNK / 2) + cc;
    float w = __expf(partialM[(b * NCHUNK + c) * 7 + s] - mg);
    den += w * partialS[(b * NCHUNK + c) * 7 + s];
    up += w * partialA[((long)(b * NCHUNK + c) * 7 + s) * 128 + d];
  }
  pp[h * 128 + d] = up;
  if (d == 0) den2[h] = den;
  if (h == 1) hs[d] = slots[blk * D_ + d];
  __syncthreads();
  if (h == 0) us[d] = (pp[d] + pp[128 + d]) / (den2[0] + den2[1]);
  __syncthreads();

  // ---- updates x = bv + us . Wv[d,:]  (split-K over h; coalesced T4 loads) ----
  {
    float acc = 0.f;
#pragma unroll
    for (int k = 0; k < 16; k++) {
      int i4 = h * 16 + k;
      acc += dot4(*reinterpret_cast<const float4*>(&us[i4 * 4]),
                  ld4(wtV + (i4 * 128 + d) * 4));
    }
    pp[h * 128 + d] = acc;
  }
  __syncthreads();
  if (h == 0) xs[d] = bv[d] + pp[d] + pp[128 + d];
  __syncthreads();

  // ---- GRU: h==0 -> gi over xs (wtIH), h==1 -> gh over hs (wtHH); R=384 ----
  {
    const float* wt = (h == 0) ? wtIH : wtHH;
    const float* bias = (h == 0) ? bih : bhh;
    const float* vec = (h == 0) ? xs : hs;
    float a0 = bias[d], a1 = bias[128 + d], a2 = bias[256 + d];
#pragma unroll
    for (int i4 = 0; i4 < 32; i4++) {
      float4 v = *reinterpret_cast<const float4*>(&vec[i4 * 4]);
      a0 += dot4(v, ld4(wt + (i4 * 384 + d) * 4));
      a1 += dot4(v, ld4(wt + (i4 * 384 + 128 + d) * 4));
      a2 += dot4(v, ld4(wt + (i4 * 384 + 256 + d) * 4));
    }
    g6[(h * 3 + 0) * 128 + d] = a0;
    g6[(h * 3 + 1) * 128 + d] = a1;
    g6[(h * 3 + 2) * 128 + d] = a2;
  }
  __syncthreads();
  if (h == 0) {
    float gir = g6[d], giz = g6[128 + d], gin = g6[256 + d];
    float ghr = g6[384 + d], ghz = g6[512 + d], ghn = g6[640 + d];
    float r = 1.f / (1.f + __expf(-(gir + ghr)));
    float z = 1.f / (1.f + __expf(-(giz + ghz)));
    float n = tanhf(gin + r * ghn);
    nss[d] = (1.f - z) * n + z * hs[d];
  }
  __syncthreads();

  // ---- LN_ff over nss ----
  if (t < 64) {
    float v0 = nss[t], v1 = nss[t + 64];
    float s1 = v0 + v1, s2 = v0 * v0 + v1 * v1;
#pragma unroll
    for (int off = 32; off >= 1; off >>= 1) { s1 += __shfl_down(s1, off); s2 += __shfl_down(s2, off); }
    if (t == 0) { red2[0] = s1; red2[1] = s2; }
  }
  __syncthreads();
  {
    float mean = red2[0] * (1.f / 128.f);
    float var = red2[1] * (1.f / 128.f) - mean * mean;
    float rs = rsqrtf(var + 1e-5f);
    if (h == 0) lns[d] = (nss[d] - mean) * rs * gff[d] + bff[d];
  }
  __syncthreads();

  // ---- FFN1: 256 outputs, one per thread (wt1, R=256) ----
  {
    float a = b1[t];
#pragma unroll
    for (int i4 = 0; i4 < 32; i4++)
      a += dot4(*reinterpret_cast<const float4*>(&lns[i4 * 4]),
                ld4(wt1 + (i4 * 256 + t) * 4));
    h1s[t] = fmaxf(a, 0.f);
  }
  __syncthreads();

  // ---- FFN2 + residual (split-K over h; wt2, R=128) ----
  {
    float acc = 0.f;
#pragma unroll
    for (int k = 0; k < 32; k++) {
      int h4 = h * 32 + k;
      acc += dot4(*reinterpret_cast<const float4*>(&h1s[h4 * 4]),
                  ld4(wt2 + (h4 * 128 + d) * 4));
    }
    pp[h * 128 + d] = acc;
  }
  __syncthreads();
  if (h == 0) {
    float out = nss[d] + b2[d] + pp[d] + pp[128 + d];
    sn[d] = out;
    slots[blk * D_ + d] = out;
  }
  __syncthreads();

  if (!compute_q) return;

  // ---- fused next-iteration q: LN_s(sn) -> q -> q' = q@Wk ----
  if (t < 64) {
    float v0 = sn[t], v1 = sn[t + 64];
    float s1 = v0 + v1, s2 = v0 * v0 + v1 * v1;
#pragma unroll
    for (int off = 32; off >= 1; off >>= 1) { s1 += __shfl_down(s1, off); s2 += __shfl_down(s2, off); }
    if (t == 0) { red2[0] = s1; red2[1] = s2; }
  }
  __syncthreads();
  {
    float mean = red2[0] * (1.f / 128.f);
    float var = red2[1] * (1.f / 128.f) - mean * mean;
    float rs = rsqrtf(var + 1e-5f);
    if (h == 0) lns[d] = (sn[d] - mean) * rs * lsg[d] + lsb[d];
  }
  __syncthreads();
  {
    float acc = 0.f;
#pragma unroll
    for (int k = 0; k < 16; k++) {
      int i4 = h * 16 + k;
      acc += dot4(*reinterpret_cast<const float4*>(&lns[i4 * 4]),
                  ld4(wtQ + (i4 * 128 + d) * 4));
    }
    pp[h * 128 + d] = acc;
  }
  __syncthreads();
  if (h == 0) qv[d] = bq[d] + pp[d] + pp[128 + d];
  __syncthreads();
  {
    float acc = 0.f;
    const float* wc = Wk + h * 64 * D_ + d;
#pragma unroll 4
    for (int dd = 0; dd < 64; dd++) acc += qv[h * 64 + dd] * wc[dd * D_];
    pp[h * 128 + d] = acc;
  }
  __syncthreads();
  if (h == 0) qp[blk * D_ + d] = pp[d] + pp[128 + d];
}

extern "C" void kernel_launch(void* const* d_in, const int* in_sizes, int n_in,
                              void* d_out, int out_size, void* d_ws, size_t ws_size,
                              hipStream_t stream) {
  const float* emb   = (const float*)d_in[0];
  const float* noise = (const float*)d_in[1];
  const float* mu    = (const float*)d_in[2];
  const float* sigma = (const float*)d_in[3];
  const float* Wk = (const float*)d_in[4];  const float* bk = (const float*)d_in[5];
  const float* Wq = (const float*)d_in[6];  const float* bq = (const float*)d_in[7];
  const float* Wv = (const float*)d_in[8];  const float* bv = (const float*)d_in[9];
  const float* Wih = (const float*)d_in[10]; const float* Whh = (const float*)d_in[11];
  const float* bih = (const float*)d_in[12]; const float* bhh = (const float*)d_in[13];
  const float* W1 = (const float*)d_in[14];  const float* b1 = (const float*)d_in[15];
  const float* W2 = (const float*)d_in[16];  const float* b2 = (const float*)d_in[17];
  const float* lin_g = (const float*)d_in[18]; const float* lin_b = (const float*)d_in[19];
  const float* ls_g  = (const float*)d_in[20]; const float* ls_b  = (const float*)d_in[21];
  const float* lff_g = (const float*)d_in[22]; const float* lff_b = (const float*)d_in[23];
  (void)bk;  // q.bk is softmax-invariant (cancels exactly)

  float* slots = (float*)d_out;  // [B,S,D] in d_out, updated in place
  float* qp       = (float*)d_ws;                              // 57,344 f
  float* partialA = qp + (size_t)B_ * S_ * D_;                 // 458,752 f
  float* partialM = partialA + (size_t)B_ * NCHUNK * S_ * D_;  // 3,584 f
  float* partialS = partialM + (size_t)B_ * NCHUNK * S_;       // 3,584 f
  // transposed weights (786 KB total), written once in the prologue
  float* wtV  = partialS + (size_t)B_ * NCHUNK * S_;           // 16,384 f
  float* wtIH = wtV + 16384;                                   // 49,152 f
  float* wtHH = wtIH + 49152;                                  // 49,152 f
  float* wtQ  = wtHH + 49152;                                  // 16,384 f
  float* wt1  = wtQ + 16384;                                   // 32,768 f
  float* wt2  = wt1 + 32768;                                   // 32,768 f

  k_init<<<224, 256, 0, stream>>>(noise, mu, sigma, slots);
  k_wt<<<64, 256, 0, stream>>>(Wv, wtV, 128, 128);
  k_wt<<<192, 256, 0, stream>>>(Wih, wtIH, 384, 128);
  k_wt<<<192, 256, 0, stream>>>(Whh, wtHH, 384, 128);
  k_wt<<<64, 256, 0, stream>>>(Wq, wtQ, 128, 128);
  k_wt<<<128, 256, 0, stream>>>(W1, wt1, 256, 128);
  k_wt<<<128, 256, 0, stream>>>(W2, wt2, 128, 256);
  k_q<<<448, 128, 0, stream>>>(slots, Wq, bq, ls_g, ls_b, Wk, qp);
  for (int it = 0; it < ITERS_; it++) {
    k_attn<<<B_ * NCHUNK, 256, 0, stream>>>(qp, emb, lin_g, lin_b, partialA, partialM, partialS);
    k_gruffq<<<448, 256, 0, stream>>>(partialA, partialM, partialS, slots, wtV, bv,
                                      wtIH, wtHH, bih, bhh, wt1, b1, wt2, b2, lff_g, lff_b,
                                      ls_g, ls_b, wtQ, bq, Wk, qp, it < ITERS_ - 1 ? 1 : 0);
  }
}